// Round 1
// baseline (636.511 us; speedup 1.0000x reference)
//
#include <hip/hip_runtime.h>
#include <hip/hip_bf16.h>

#define D_IN   512
#define D_OUT  512
#define BATCH  64
#define GRID_N 100
#define OC_SIZE 16                       // output cols per block
#define IC_SIZE 16                       // input rows per block
#define F4_PER_SLAB (OC_SIZE * GRID_N)   // 1600 float4 = 25.6 KB
#define PITCH 101                        // float4 granules per o-row in LDS (pad +1)
#define I_STRIDE_F4 (D_OUT * GRID_N)     // 51200 float4 per i

// ---------------- Phase 1: LayerNorm + grid index + Bernstein basis ----------------
__global__ __launch_bounds__(256) void kan_ln_basis(
    const float* __restrict__ x, const float* __restrict__ lnw,
    const float* __restrict__ lnb, const float* __restrict__ M,
    float4* __restrict__ basisT, int* __restrict__ idxT)
{
    int b = blockIdx.x;
    int t = threadIdx.x;
    __shared__ float red[4];
    __shared__ float sM[16];
    __shared__ float sstat[2];

    if (t < 16) sM[t] = M[t];

    float x0 = x[b * D_IN + t];
    float x1 = x[b * D_IN + 256 + t];

    // pass 1: mean
    float s = x0 + x1;
    #pragma unroll
    for (int m = 32; m >= 1; m >>= 1) s += __shfl_xor(s, m, 64);
    int wid = t >> 6, lane = t & 63;
    if (lane == 0) red[wid] = s;
    __syncthreads();
    if (t == 0) sstat[0] = (red[0] + red[1] + red[2] + red[3]) * (1.0f / 512.0f);
    __syncthreads();
    float mean = sstat[0];

    // pass 2: variance (two-pass, matches jnp.var closely)
    float d0 = x0 - mean, d1 = x1 - mean;
    float v = d0 * d0 + d1 * d1;
    #pragma unroll
    for (int m = 32; m >= 1; m >>= 1) v += __shfl_xor(v, m, 64);
    __syncthreads();              // red re-use hazard
    if (lane == 0) red[wid] = v;
    __syncthreads();
    if (t == 0) sstat[1] = (red[0] + red[1] + red[2] + red[3]) * (1.0f / 512.0f);
    __syncthreads();
    float var = sstat[1];
    float rs = 1.0f / sqrtf(var + 1e-5f);

    #pragma unroll
    for (int e = 0; e < 2; ++e) {
        int i = t + e * 256;
        float xv = (e == 0) ? x0 : x1;
        float xn = (xv - mean) * rs * lnw[i] + lnb[i];
        xn = fminf(fmaxf(xn, -1.0f + 1e-6f), 1.0f - 1e-6f);
        xn = (xn + 1.0f) * 0.5f;
        float sc = xn * 100.0f;
        float fl = floorf(sc);
        int g = (int)fl;
        if (g > 99) g = 99;
        if (g < 0)  g = 0;
        float tt = sc - fl;
        float t2 = tt * tt, t3 = t2 * tt;
        float4 bs;
        bs.x = sM[0] + tt * sM[4] + t2 * sM[8]  + t3 * sM[12];
        bs.y = sM[1] + tt * sM[5] + t2 * sM[9]  + t3 * sM[13];
        bs.z = sM[2] + tt * sM[6] + t2 * sM[10] + t3 * sM[14];
        bs.w = sM[3] + tt * sM[7] + t2 * sM[11] + t3 * sM[15];
        idxT[i * BATCH + b] = g;
        basisT[i * BATCH + b] = bs;
    }
}

// ---------------- Phase 2: stream poly_matrix, LDS-staged gather-accumulate --------
__global__ __launch_bounds__(256) void kan_gather(
    const float4* __restrict__ P4, const float4* __restrict__ basisT,
    const int* __restrict__ idxT, float* __restrict__ out)
{
    __shared__ float4 slab[OC_SIZE * PITCH];   // 25,856 B
    __shared__ float4 sbasis[BATCH];           // 1 KB
    __shared__ int    sidx[BATCH];             // 256 B

    int t  = threadIdx.x;
    int oc = blockIdx.x & 31;        // 32 o-chunks
    int ic = blockIdx.x >> 5;        // 32 i-chunks

    // per-thread staging map (invariant over the i loop)
    int  ldsoff[7];
    int  gf[7];
    bool act[7];
    #pragma unroll
    for (int c = 0; c < 7; ++c) {
        int f = c * 256 + t;
        act[c] = (f < F4_PER_SLAB);
        int o  = f / GRID_N;
        int g4 = f - o * GRID_N;
        ldsoff[c] = o * PITCH + g4;
        gf[c] = f;
    }

    int i0 = ic * IC_SIZE;
    const float4* Pb = P4 + (size_t)i0 * I_STRIDE_F4 + (size_t)oc * F4_PER_SLAB;

    // prefetch slab 0 + meta 0 into registers
    float4 r[7];
    float4 rb;
    int    ri = 0;
    #pragma unroll
    for (int c = 0; c < 7; ++c) if (act[c]) r[c] = Pb[gf[c]];
    if (t < BATCH) { ri = idxT[i0 * BATCH + t]; rb = basisT[i0 * BATCH + t]; }

    float acc[4] = {0.f, 0.f, 0.f, 0.f};
    int o  = t & 15;
    int bq = t >> 4;

    for (int ii = 0; ii < IC_SIZE; ++ii) {
        __syncthreads();                       // LDS free from previous compute
        #pragma unroll
        for (int c = 0; c < 7; ++c) if (act[c]) slab[ldsoff[c]] = r[c];
        if (t < BATCH) { sidx[t] = ri; sbasis[t] = rb; }
        __syncthreads();

        if (ii + 1 < IC_SIZE) {                // prefetch next slab while computing
            Pb += I_STRIDE_F4;
            #pragma unroll
            for (int c = 0; c < 7; ++c) if (act[c]) r[c] = Pb[gf[c]];
            int i = i0 + ii + 1;
            if (t < BATCH) { ri = idxT[i * BATCH + t]; rb = basisT[i * BATCH + t]; }
        }

        #pragma unroll
        for (int bb = 0; bb < 4; ++bb) {
            int b = bb * 16 + bq;
            int g = sidx[b];
            float4 bs = sbasis[b];
            float4 pv = slab[o * PITCH + g];
            acc[bb] += bs.x * pv.x + bs.y * pv.y + bs.z * pv.z + bs.w * pv.w;
        }
    }

    int ocol = oc * OC_SIZE + o;
    #pragma unroll
    for (int bb = 0; bb < 4; ++bb) {
        int b = bb * 16 + bq;
        atomicAdd(&out[b * D_OUT + ocol], acc[bb]);
    }
}

extern "C" void kernel_launch(void* const* d_in, const int* in_sizes, int n_in,
                              void* d_out, int out_size, void* d_ws, size_t ws_size,
                              hipStream_t stream) {
    const float* x   = (const float*)d_in[0];
    const float* P   = (const float*)d_in[1];
    const float* lnw = (const float*)d_in[2];
    const float* lnb = (const float*)d_in[3];
    const float* M   = (const float*)d_in[4];
    float* out = (float*)d_out;

    float4* basisT = (float4*)d_ws;                                // 512*64*16 B = 524,288
    int*    idxT   = (int*)((char*)d_ws + D_IN * BATCH * 16);      // 131,072 B

    hipMemsetAsync(d_out, 0, BATCH * D_OUT * sizeof(float), stream);
    kan_ln_basis<<<BATCH, 256, 0, stream>>>(x, lnw, lnb, M, basisT, idxT);
    kan_gather<<<1024, 256, 0, stream>>>((const float4*)P, basisT, idxT, out);
}